// Round 2
// 829.939 us; speedup vs baseline: 1.1820x; 1.1820x over previous
//
#include <hip/hip_runtime.h>
#include <cstddef>

// B=64, T=512, H=256. Float inputs fp32 (runtime-detected, bf16 fallback).
// Output fp32: [out_s (B*T), out_e (B*T)].
// ws layout (bytes):
//   0        W5q   640*256 u32 bf16-pair B-frags, uint4-grouped:
//                  idx = ((p>>2)*256+col)*4+(p&3); p: 0..127 W1f, 128..255
//                  W1fq+W1fm, 256..383 W1afq+afm, 384..511 Wr, 512..639 Wh
//   1310720  Urp   128*256 u32  (bf16 pairs along i)
//   1441792  Uhp   128*256 u32
//   1572864  qw1   64*256 f32
//   1638400  qs    64 f32
//   1638656  qe    64 f32
//   1638912  att   64*512 f32
//   1769984  g     64*512 f32
//   1901056  xrh   64*512*256 u32
//   35455488 ep    64*512*256 bf16
//   52232704 mode  int

static __device__ __forceinline__ float b2f(unsigned short u) {
  return __uint_as_float(((unsigned)u) << 16);
}
static __device__ __forceinline__ float blo(unsigned w) { return __uint_as_float(w << 16); }
static __device__ __forceinline__ float bhi(unsigned w) { return __uint_as_float(w & 0xffff0000u); }
static __device__ __forceinline__ unsigned short f2b(float f) {
  unsigned u = __float_as_uint(f);
  u += 0x7fffu + ((u >> 16) & 1u);  // RNE
  return (unsigned short)(u >> 16);
}
static __device__ __forceinline__ float ldf(const void* b, size_t i, int md) {
  return md ? ((const float*)b)[i] : b2f(((const unsigned short*)b)[i]);
}
static __device__ __forceinline__ unsigned short ldb(const void* b, size_t i, int md) {
  return md ? f2b(((const float*)b)[i]) : ((const unsigned short*)b)[i];
}

typedef short bfrag __attribute__((ext_vector_type(8)));
typedef float f32x4 __attribute__((ext_vector_type(4)));

template <int CTRL>
static __device__ __forceinline__ float dpp_add(float x) {
  int v = __builtin_amdgcn_update_dpp(0, __float_as_int(x), CTRL, 0xF, 0xF, true);
  return x + __int_as_float(v);
}
static __device__ __forceinline__ float red16(float x) {
  x = dpp_add<0xB1>(x);
  x = dpp_add<0x4E>(x);
  x = dpp_add<0x141>(x);
  x = dpp_add<0x140>(x);
  return x;
}
static __device__ __forceinline__ void sync_lds() {
  __builtin_amdgcn_fence(__ATOMIC_RELEASE, "workgroup", "local");
  __builtin_amdgcn_s_barrier();
  __builtin_amdgcn_fence(__ATOMIC_ACQUIRE, "workgroup", "local");
}
static __device__ __forceinline__ float fast_tanh(float x) {
  float xc = fminf(fmaxf(x, -15.f), 15.f);
  return 1.f - 2.f * __builtin_amdgcn_rcpf(__expf(2.f * xc) + 1.f);
}

// ---------------- dtype detection ----------------
__global__ void k_detect(const void* __restrict__ fact, int* __restrict__ mode) {
  int tid = threadIdx.x;  // 256
  const unsigned short* u = (const unsigned short*)fact;
  float v = fabsf(b2f(u[2 * tid]));
  if (!(v == v)) v = 1e30f;
  for (int o = 32; o > 0; o >>= 1) v = fmaxf(v, __shfl_xor(v, o));
  __shared__ float red[4];
  int wave = tid >> 6, lane = tid & 63;
  if (lane == 0) red[wave] = v;
  __syncthreads();
  if (tid == 0) {
    float m = fmaxf(fmaxf(red[0], red[1]), fmaxf(red[2], red[3]));
    mode[0] = (m > 1e4f) ? 1 : 0;
  }
}

// ---------------- prep: packed bf16 weights ----------------
__global__ void k_prep_w(const void* __restrict__ W1,
                         const void* __restrict__ Wr,
                         const void* __restrict__ Wh,
                         const void* __restrict__ Ur,
                         const void* __restrict__ Uh,
                         const int* __restrict__ mode,
                         unsigned* __restrict__ W5q,
                         unsigned* __restrict__ Urp,
                         unsigned* __restrict__ Uhp) {
  int md = *mode;
  int idx = blockIdx.x * 256 + threadIdx.x;  // 0..32767
  int i = idx >> 8, j = idx & 255;
  Urp[idx] = (unsigned)ldb(Ur, (size_t)(2 * i) * 256 + j, md) |
             ((unsigned)ldb(Ur, (size_t)(2 * i + 1) * 256 + j, md) << 16);
  Uhp[idx] = (unsigned)ldb(Uh, (size_t)(2 * i) * 256 + j, md) |
             ((unsigned)ldb(Uh, (size_t)(2 * i + 1) * 256 + j, md) << 16);
  float v0, v1;
  int p;
  p = i;
  v0 = ldf(W1, (size_t)(2 * i) * 256 + j, md);
  v1 = ldf(W1, (size_t)(2 * i + 1) * 256 + j, md);
  W5q[(((p >> 2) * 256 + j) << 2) + (p & 3)] = (unsigned)f2b(v0) | ((unsigned)f2b(v1) << 16);
  p = 128 + i;
  v0 = ldf(W1, (size_t)(768 + 2 * i) * 256 + j, md) + ldf(W1, (size_t)(1024 + 2 * i) * 256 + j, md);
  v1 = ldf(W1, (size_t)(769 + 2 * i) * 256 + j, md) + ldf(W1, (size_t)(1025 + 2 * i) * 256 + j, md);
  W5q[(((p >> 2) * 256 + j) << 2) + (p & 3)] = (unsigned)f2b(v0) | ((unsigned)f2b(v1) << 16);
  p = 256 + i;
  v0 = ldf(W1, (size_t)(1280 + 2 * i) * 256 + j, md) + ldf(W1, (size_t)(1536 + 2 * i) * 256 + j, md);
  v1 = ldf(W1, (size_t)(1281 + 2 * i) * 256 + j, md) + ldf(W1, (size_t)(1537 + 2 * i) * 256 + j, md);
  W5q[(((p >> 2) * 256 + j) << 2) + (p & 3)] = (unsigned)f2b(v0) | ((unsigned)f2b(v1) << 16);
  p = 384 + i;
  v0 = ldf(Wr, (size_t)(2 * i) * 256 + j, md);
  v1 = ldf(Wr, (size_t)(2 * i + 1) * 256 + j, md);
  W5q[(((p >> 2) * 256 + j) << 2) + (p & 3)] = (unsigned)f2b(v0) | ((unsigned)f2b(v1) << 16);
  p = 512 + i;
  v0 = ldf(Wh, (size_t)(2 * i) * 256 + j, md);
  v1 = ldf(Wh, (size_t)(2 * i + 1) * 256 + j, md);
  W5q[(((p >> 2) * 256 + j) << 2) + (p & 3)] = (unsigned)f2b(v0) | ((unsigned)f2b(v1) << 16);
}

// ---------------- prep: q-dependent vectors ----------------
__global__ void k_prep_q(const void* __restrict__ q,
                         const void* __restrict__ W1,
                         const void* __restrict__ b1,
                         const void* __restrict__ Ws,
                         const void* __restrict__ bs,
                         const void* __restrict__ We,
                         const void* __restrict__ be,
                         const int* __restrict__ mode,
                         float* __restrict__ qw1,
                         float* __restrict__ qs,
                         float* __restrict__ qe) {
  __shared__ float qsh[256];
  __shared__ float reds[4], rede[4];
  int md = *mode;
  int b = blockIdx.x, tid = threadIdx.x;
  float qv = ldf(q, (size_t)b * 256 + tid, md);
  qsh[tid] = qv;
  __syncthreads();
  float acc = ldf(b1, tid, md);
  for (int i = 0; i < 256; ++i) {
    float w = ldf(W1, (size_t)(256 + i) * 256 + tid, md) + ldf(W1, (size_t)(512 + i) * 256 + tid, md);
    acc = fmaf(qsh[i], w, acc);
  }
  qw1[b * 256 + tid] = acc;
  float ps = qv * ldf(Ws, tid, md);
  float pe = qv * ldf(We, tid, md);
  for (int o = 32; o > 0; o >>= 1) { ps += __shfl_down(ps, o); pe += __shfl_down(pe, o); }
  int wave = tid >> 6, lane = tid & 63;
  if (lane == 0) { reds[wave] = ps; rede[wave] = pe; }
  __syncthreads();
  if (tid == 0) {
    qs[b] = ldf(bs, 0, md) + reds[0] + reds[1] + reds[2] + reds[3];
    qe[b] = ldf(be, 0, md) + rede[0] + rede[1] + rede[2] + rede[3];
  }
}

// ---------------- main GEMM via MFMA: att pre-softmax + xr/xh ----------------
__launch_bounds__(256, 2)
__global__ void k_main(const void* __restrict__ fact,
                       const void* __restrict__ q,
                       const unsigned* __restrict__ W5q,
                       const float* __restrict__ qw1,
                       const void* __restrict__ W2,
                       const void* __restrict__ b2v,
                       const void* __restrict__ br,
                       const void* __restrict__ bh,
                       const int* __restrict__ mode,
                       float* __restrict__ att,
                       unsigned* __restrict__ xrh) {
  __shared__ __align__(16) unsigned short A[16 * 776];
  __shared__ float wsc[64];
  int md = *mode;
  int blk = blockIdx.x;
  int b = blk >> 5, t0 = (blk & 31) * 16;
  int tid = threadIdx.x;
  {
    float qv = ldf(q, (size_t)b * 256 + tid, md);
    for (int r = 0; r < 16; ++r) {
      float f = ldf(fact, ((size_t)(b * 512 + t0 + r)) * 256 + tid, md);
      A[r * 776 + tid] = f2b(f);
      A[r * 776 + 256 + tid] = f2b(f * qv);
      A[r * 776 + 512 + tid] = f2b(fabsf(f - qv));
    }
  }
  __syncthreads();
  int wv = tid >> 6, lane = tid & 63;
  int n16 = lane & 15, quad = lane >> 4;
  int colb = wv * 64 + n16;
  const uint4* W4 = (const uint4*)W5q;
  f32x4 z = {0.f, 0.f, 0.f, 0.f};
  f32x4 u[4] = {z, z, z, z}, ar[4] = {z, z, z, z}, ah[4] = {z, z, z, z};
#pragma unroll
  for (int kc = 0; kc < 8; ++kc) {
    uint4 av = *(const uint4*)((const char*)A + n16 * 1552 + kc * 64 + quad * 16);
    bfrag af = __builtin_bit_cast(bfrag, av);
    int pg = kc * 4 + quad;
#pragma unroll
    for (int tile = 0; tile < 4; ++tile) {
      int col = colb + tile * 16;
      uint4 bu = W4[(size_t)pg * 256 + col];
      uint4 bw = W4[(size_t)(96 + pg) * 256 + col];
      uint4 bv = W4[(size_t)(128 + pg) * 256 + col];
      u[tile] = __builtin_amdgcn_mfma_f32_16x16x32_bf16(af, __builtin_bit_cast(bfrag, bu), u[tile], 0, 0, 0);
      ar[tile] = __builtin_amdgcn_mfma_f32_16x16x32_bf16(af, __builtin_bit_cast(bfrag, bw), ar[tile], 0, 0, 0);
      ah[tile] = __builtin_amdgcn_mfma_f32_16x16x32_bf16(af, __builtin_bit_cast(bfrag, bv), ah[tile], 0, 0, 0);
    }
  }
#pragma unroll
  for (int kc = 8; kc < 24; ++kc) {
    uint4 av = *(const uint4*)((const char*)A + n16 * 1552 + kc * 64 + quad * 16);
    bfrag af = __builtin_bit_cast(bfrag, av);
    int pg = kc * 4 + quad;
#pragma unroll
    for (int tile = 0; tile < 4; ++tile) {
      int col = colb + tile * 16;
      uint4 bu = W4[(size_t)pg * 256 + col];
      u[tile] = __builtin_amdgcn_mfma_f32_16x16x32_bf16(af, __builtin_bit_cast(bfrag, bu), u[tile], 0, 0, 0);
    }
  }
  float qwv[4], w2v[4], brv[4], bhv[4];
#pragma unroll
  for (int tile = 0; tile < 4; ++tile) {
    int col = colb + tile * 16;
    qwv[tile] = qw1[b * 256 + col];
    w2v[tile] = ldf(W2, col, md);
    brv[tile] = ldf(br, col, md);
    bhv[tile] = ldf(bh, col, md);
  }
  float ps[4];
#pragma unroll
  for (int reg = 0; reg < 4; ++reg) {
    float p = 0.f;
#pragma unroll
    for (int tile = 0; tile < 4; ++tile) {
      float hid = fast_tanh(u[tile][reg] + qwv[tile]);
      p = fmaf(hid, w2v[tile], p);
    }
    ps[reg] = red16(p);
  }
  if (n16 == 0) {
#pragma unroll
    for (int reg = 0; reg < 4; ++reg) wsc[wv * 16 + quad * 4 + reg] = ps[reg];
  }
  __syncthreads();
  if (tid < 16) {
    att[b * 512 + t0 + tid] =
        wsc[tid] + wsc[16 + tid] + wsc[32 + tid] + wsc[48 + tid] + ldf(b2v, 0, md);
  }
#pragma unroll
  for (int tile = 0; tile < 4; ++tile) {
    int col = colb + tile * 16;
#pragma unroll
    for (int reg = 0; reg < 4; ++reg) {
      int t = t0 + quad * 4 + reg;
      unsigned v = (unsigned)f2b(ar[tile][reg] + brv[tile]) |
                   ((unsigned)f2b(ah[tile][reg] + bhv[tile]) << 16);
      xrh[((size_t)(b * 512 + t)) * 256 + col] = v;
    }
  }
}

// ---------------- softmax over T per batch ----------------
__global__ void k_softmax(const float* __restrict__ att, float* __restrict__ g) {
  __shared__ float red[8];
  int b = blockIdx.x, tid = threadIdx.x;  // 512 threads
  float v = att[b * 512 + tid];
  float m = v;
  for (int o = 32; o > 0; o >>= 1) m = fmaxf(m, __shfl_xor(m, o));
  int wave = tid >> 6, lane = tid & 63;
  if (lane == 0) red[wave] = m;
  __syncthreads();
  m = red[0];
#pragma unroll
  for (int w = 1; w < 8; ++w) m = fmaxf(m, red[w]);
  float e = __expf(v - m);
  float s = e;
  for (int o = 32; o > 0; o >>= 1) s += __shfl_xor(s, o);
  __syncthreads();
  if (lane == 0) red[wave] = s;
  __syncthreads();
  s = red[0] + red[1] + red[2] + red[3] + red[4] + red[5] + red[6] + red[7];
  g[b * 512 + tid] = e / s;
}

// ---------------- MFMA GRU scan: 4 batches/block, 16 blocks, 8 waves ----------------
// 512 threads = 8 waves (2/SIMD). Wave wv owns cols [wv*32, wv*32+32) as 2
// N-tiles -> B-frags stored as uint4 (no per-step repack).
// A-row remap: A row m (= lane&15) now holds batch m>>2 (was m&3), so the
// C/D row quad*4+reg has batch==quad for every reg -> EVERY lane owns
// (batch=quad, cols col0/col1) and the sigmoid/tanh sections run on all 64
// lanes with 2 serial chains (was: 32 lanes x 4 chains). MFMA chains split
// depth 4 -> depth 2 (8 independent accumulators, only elem [0] consumed).
// xb padded to stride 264 dwords (4-quads-same-col read would be 4-way
// conflicted at 256); eb rotated by quad*16 cols to keep writes 2-way.
__launch_bounds__(512, 2)
__global__ void k_scan(const unsigned* __restrict__ Urp,
                       const unsigned* __restrict__ Uhp,
                       const unsigned* __restrict__ xrh,
                       const float* __restrict__ g,
                       const int* __restrict__ input_len,
                       unsigned short* __restrict__ ep) {
  __shared__ __align__(16) unsigned short hB[4 * 272];
  __shared__ __align__(16) unsigned short rhB[4 * 272];
  __shared__ float gsh[4 * 512];
  __shared__ __align__(16) unsigned xb[8 * 4 * 264];        // 33 KB (padded)
  __shared__ __align__(16) unsigned short eb[8 * 4 * 256];  // 16 KB
  int b0 = blockIdx.x * 4;
  int tid = threadIdx.x;  // 0..511
  int wv = tid >> 6, lane = tid & 63;
  int n16 = lane & 15, quad = lane >> 4;
  int col0 = wv * 32 + n16;
  int col1 = col0 + 16;
  uint4 br4[2][8], bh4[2][8];
#pragma unroll
  for (int tile = 0; tile < 2; ++tile) {
    int col = wv * 32 + tile * 16 + n16;
#pragma unroll
    for (int kc = 0; kc < 8; ++kc) {
      int p = kc * 16 + quad * 4;
      uint4 rv = {Urp[(size_t)p * 256 + col], Urp[(size_t)(p + 1) * 256 + col],
                  Urp[(size_t)(p + 2) * 256 + col], Urp[(size_t)(p + 3) * 256 + col]};
      uint4 hv = {Uhp[(size_t)p * 256 + col], Uhp[(size_t)(p + 1) * 256 + col],
                  Uhp[(size_t)(p + 2) * 256 + col], Uhp[(size_t)(p + 3) * 256 + col]};
      br4[tile][kc] = rv;
      bh4[tile][kc] = hv;
    }
  }
  for (int i = tid; i < 2048; i += 512)
    gsh[i] = g[(size_t)(b0 + (i >> 9)) * 512 + (i & 511)];
  for (int i = tid; i < 4 * 272; i += 512) { hB[i] = 0; rhB[i] = 0; }
  int mylen = input_len[b0 + quad];
  float hm0 = 0.f, hm1 = 0.f;  // this lane's h for (batch=quad, col0/col1)
  const char* hbase = (const char*)hB + (n16 >> 2) * 544 + quad * 16;
  const char* rhbase = (const char*)rhB + (n16 >> 2) * 544 + quad * 16;
  uint4 pf[4];
#pragma unroll
  for (int k = 0; k < 4; ++k) {
    int i = tid + k * 512;
    int s = i >> 8, rem = i & 255, m = rem >> 6, jc = rem & 63;
    pf[k] = ((const uint4*)(xrh + ((size_t)(b0 + m) * 512 + s) * 256))[jc];
  }
  __syncthreads();
  const f32x4 z4 = {0.f, 0.f, 0.f, 0.f};
  for (int t = 0; t < 512; ++t) {
    int tt = t & 7;
    if (tt == 0) {
      if (t != 0) {
#pragma unroll
        for (int k = 0; k < 2; ++k) {
          int i = tid + k * 512;
          int sm = i >> 5, jc = i & 31;
          int s = sm >> 2, m = sm & 3;
          uint4 ev = ((const uint4*)eb)[sm * 32 + ((jc + 2 * m) & 31)];
          ((uint4*)(ep + ((size_t)(b0 + m) * 512 + (t - 8 + s)) * 256))[jc] = ev;
        }
      }
#pragma unroll
      for (int k = 0; k < 4; ++k) {
        int i = tid + k * 512;
        int s = i >> 8, rem = i & 255, m = rem >> 6, jc = rem & 63;
        ((uint4*)xb)[(s * 4 + m) * 66 + jc] = pf[k];
      }
      sync_lds();
      if (t < 504) {
        int tb = (t >> 3) + 1;
#pragma unroll
        for (int k = 0; k < 4; ++k) {
          int i = tid + k * 512;
          int s = i >> 8, rem = i & 255, m = rem >> 6, jc = rem & 63;
          pf[k] = ((const uint4*)(xrh + ((size_t)(b0 + m) * 512 + tb * 8 + s) * 256))[jc];
        }
      }
    }
    unsigned xc0 = xb[(tt * 4 + quad) * 264 + col0];
    unsigned xc1 = xb[(tt * 4 + quad) * 264 + col1];
    float gt = gsh[quad * 512 + t];
    // ---- phase A: rpre = h @ Ur (2 tiles, depth-2 chains) ----
    f32x4 accA[2][4];
#pragma unroll
    for (int tl = 0; tl < 2; ++tl)
#pragma unroll
      for (int j = 0; j < 4; ++j) accA[tl][j] = z4;
#pragma unroll
    for (int kc = 0; kc < 8; ++kc) {
      uint4 av = *(const uint4*)(hbase + kc * 64);
      bfrag af = __builtin_bit_cast(bfrag, av);
      int j = kc & 3;
      accA[0][j] = __builtin_amdgcn_mfma_f32_16x16x32_bf16(af, __builtin_bit_cast(bfrag, br4[0][kc]), accA[0][j], 0, 0, 0);
      accA[1][j] = __builtin_amdgcn_mfma_f32_16x16x32_bf16(af, __builtin_bit_cast(bfrag, br4[1][kc]), accA[1][j], 0, 0, 0);
    }
    {
      float v0 = (accA[0][0][0] + accA[0][1][0]) + (accA[0][2][0] + accA[0][3][0]);
      float v1 = (accA[1][0][0] + accA[1][1][0]) + (accA[1][2][0] + accA[1][3][0]);
      float e0 = __expf(-(v0 + blo(xc0)));
      float e1 = __expf(-(v1 + blo(xc1)));
      float r0 = __builtin_amdgcn_rcpf(1.f + e0);
      float r1 = __builtin_amdgcn_rcpf(1.f + e1);
      rhB[quad * 272 + col0] = f2b(r0 * hm0);
      rhB[quad * 272 + col1] = f2b(r1 * hm1);
    }
    sync_lds();
    // ---- phase B: hpre = (r*h) @ Uh ----
    f32x4 accB[2][4];
#pragma unroll
    for (int tl = 0; tl < 2; ++tl)
#pragma unroll
      for (int j = 0; j < 4; ++j) accB[tl][j] = z4;
#pragma unroll
    for (int kc = 0; kc < 8; ++kc) {
      uint4 av = *(const uint4*)(rhbase + kc * 64);
      bfrag af = __builtin_bit_cast(bfrag, av);
      int j = kc & 3;
      accB[0][j] = __builtin_amdgcn_mfma_f32_16x16x32_bf16(af, __builtin_bit_cast(bfrag, bh4[0][kc]), accB[0][j], 0, 0, 0);
      accB[1][j] = __builtin_amdgcn_mfma_f32_16x16x32_bf16(af, __builtin_bit_cast(bfrag, bh4[1][kc]), accB[1][j], 0, 0, 0);
    }
    {
      float w0 = (accB[0][0][0] + accB[0][1][0]) + (accB[0][2][0] + accB[0][3][0]);
      float w1 = (accB[1][0][0] + accB[1][1][0]) + (accB[1][2][0] + accB[1][3][0]);
      float c0 = fminf(fmaxf(w0 + bhi(xc0), -15.f), 15.f);
      float c1 = fminf(fmaxf(w1 + bhi(xc1), -15.f), 15.f);
      float hc0 = 1.f - 2.f * __builtin_amdgcn_rcpf(__expf(2.f * c0) + 1.f);
      float hc1 = 1.f - 2.f * __builtin_amdgcn_rcpf(__expf(2.f * c1) + 1.f);
      bool valid = t < mylen;
      float hn0 = hm0 + gt * (hc0 - hm0);
      float hn1 = hm1 + gt * (hc1 - hm1);
      hm0 = valid ? hn0 : hm0;
      hm1 = valid ? hn1 : hm1;
      unsigned short hb0 = f2b(hm0), hb1 = f2b(hm1);
      hB[quad * 272 + col0] = hb0;
      hB[quad * 272 + col1] = hb1;
      int ebase = (tt * 4 + quad) << 8;
      eb[ebase + ((col0 + quad * 16) & 255)] = valid ? hb0 : (unsigned short)0;
      eb[ebase + ((col1 + quad * 16) & 255)] = valid ? hb1 : (unsigned short)0;
    }
    sync_lds();
  }
#pragma unroll
  for (int k = 0; k < 2; ++k) {
    int i = tid + k * 512;
    int sm = i >> 5, jc = i & 31;
    int s = sm >> 2, m = sm & 3;
    uint4 ev = ((const uint4*)eb)[sm * 32 + ((jc + 2 * m) & 31)];
    ((uint4*)(ep + ((size_t)(b0 + m) * 512 + (504 + s)) * 256))[jc] = ev;
  }
}

// ---------------- final dense: out_s/out_e (fp32 output) ----------------
__global__ void k_out(const unsigned short* __restrict__ ep,
                      const void* __restrict__ Ws,
                      const void* __restrict__ We,
                      const float* __restrict__ qs,
                      const float* __restrict__ qe,
                      const int* __restrict__ mode,
                      float* __restrict__ out) {
  int md = *mode;
  int tid = threadIdx.x;
  int wave = tid >> 6, lane = tid & 63;
  int row = blockIdx.x * 4 + wave;  // (b,t) flat, 0..32767
  const unsigned short* er = ep + (size_t)row * 256 + lane * 4;
  float f0 = b2f(er[0]), f1 = b2f(er[1]), f2 = b2f(er[2]), f3 = b2f(er[3]);
  int n = 256 + lane * 4;
  float s = f0 * ldf(Ws, n, md) + f1 * ldf(Ws, n + 1, md) + f2 * ldf(Ws, n + 2, md) + f3 * ldf(Ws, n + 3, md);
  float e = f0 * ldf(We, n, md) + f1 * ldf(We, n + 1, md) + f2 * ldf(We, n + 2, md) + f3 * ldf(We, n + 3, md);
  for (int o = 32; o > 0; o >>= 1) { s += __shfl_down(s, o); e += __shfl_down(e, o); }
  if (lane == 0) {
    int b = row >> 9;
    out[row] = tanhf(qs[b] + s);
    out[32768 + row] = tanhf(qe[b] + e);
  }
}

extern "C" void kernel_launch(void* const* d_in, const int* in_sizes, int n_in,
                              void* d_out, int out_size, void* d_ws, size_t ws_size,
                              hipStream_t stream) {
  const void* q    = d_in[0];
  const void* fact = d_in[1];
  const int* ilen  = (const int*)d_in[2];
  const void* W1   = d_in[3];
  const void* b1   = d_in[4];
  const void* W2   = d_in[5];
  const void* b2v  = d_in[6];
  const void* Wr   = d_in[7];
  const void* Ur   = d_in[8];
  const void* br   = d_in[9];
  const void* Wh   = d_in[10];
  const void* Uh   = d_in[11];
  const void* bh   = d_in[12];
  const void* Ws   = d_in[13];
  const void* bs   = d_in[14];
  const void* We   = d_in[15];
  const void* be   = d_in[16];

  char* w = (char*)d_ws;
  unsigned* W5q = (unsigned*)(w);
  unsigned* Urp = (unsigned*)(w + 1310720);
  unsigned* Uhp = (unsigned*)(w + 1441792);
  float*    qw1 = (float*)(w + 1572864);
  float*    qs  = (float*)(w + 1638400);
  float*    qe  = (float*)(w + 1638656);
  float*    att = (float*)(w + 1638912);
  float*    g   = (float*)(w + 1769984);
  unsigned* xrh = (unsigned*)(w + 1901056);
  unsigned short* ep = (unsigned short*)(w + 35455488);
  int*      mode = (int*)(w + 52232704);
  float* out = (float*)d_out;

  k_detect<<<dim3(1), dim3(256), 0, stream>>>(fact, mode);
  k_prep_w<<<dim3(128), dim3(256), 0, stream>>>(W1, Wr, Wh, Ur, Uh, mode, W5q, Urp, Uhp);
  k_prep_q<<<dim3(64), dim3(256), 0, stream>>>(q, W1, b1, Ws, bs, We, be, mode, qw1, qs, qe);
  k_main<<<dim3(2048), dim3(256), 0, stream>>>(fact, q, W5q, qw1, W2, b2v, br, bh, mode, att, xrh);
  k_softmax<<<dim3(64), dim3(512), 0, stream>>>(att, g);
  k_scan<<<dim3(16), dim3(512), 0, stream>>>(Urp, Uhp, xrh, g, ilen, ep);
  k_out<<<dim3(8192), dim3(256), 0, stream>>>(ep, Ws, We, qs, qe, mode, out);
}

// Round 3
// 677.975 us; speedup vs baseline: 1.4469x; 1.2241x over previous
//
#include <hip/hip_runtime.h>
#include <cstddef>

// B=64, T=512, H=256. Float inputs fp32 (runtime-detected, bf16 fallback).
// Output fp32: [out_s (B*T), out_e (B*T)].
// ws layout (bytes):
//   0        W5q   640*256 u32 bf16-pair B-frags, uint4-grouped:
//                  idx = ((p>>2)*256+col)*4+(p&3); p: 0..127 W1f, 128..255
//                  W1fq+W1fm, 256..383 W1afq+afm, 384..511 Wr, 512..639 Wh
//   1310720  Urp   128*256 u32  (bf16 pairs along i)
//   1441792  Uhp   128*256 u32
//   1572864  qw1   64*256 f32
//   1638400  qs    64 f32
//   1638656  qe    64 f32
//   1638912  att   64*512 f32
//   1769984  g     64*512 f32
//   1901056  xrh   64*512*256 u32
//   35455488 ep    64*512*256 bf16
//   52232704 mode  int

static __device__ __forceinline__ float b2f(unsigned short u) {
  return __uint_as_float(((unsigned)u) << 16);
}
static __device__ __forceinline__ float blo(unsigned w) { return __uint_as_float(w << 16); }
static __device__ __forceinline__ float bhi(unsigned w) { return __uint_as_float(w & 0xffff0000u); }
static __device__ __forceinline__ unsigned short f2b(float f) {
  unsigned u = __float_as_uint(f);
  u += 0x7fffu + ((u >> 16) & 1u);  // RNE
  return (unsigned short)(u >> 16);
}
static __device__ __forceinline__ float ldf(const void* b, size_t i, int md) {
  return md ? ((const float*)b)[i] : b2f(((const unsigned short*)b)[i]);
}
static __device__ __forceinline__ unsigned short ldb(const void* b, size_t i, int md) {
  return md ? f2b(((const float*)b)[i]) : ((const unsigned short*)b)[i];
}

typedef short bfrag __attribute__((ext_vector_type(8)));
typedef float f32x4 __attribute__((ext_vector_type(4)));

template <int CTRL>
static __device__ __forceinline__ float dpp_add(float x) {
  int v = __builtin_amdgcn_update_dpp(0, __float_as_int(x), CTRL, 0xF, 0xF, true);
  return x + __int_as_float(v);
}
static __device__ __forceinline__ float red16(float x) {
  x = dpp_add<0xB1>(x);
  x = dpp_add<0x4E>(x);
  x = dpp_add<0x141>(x);
  x = dpp_add<0x140>(x);
  return x;
}
static __device__ __forceinline__ void sync_lds() {
  __builtin_amdgcn_fence(__ATOMIC_RELEASE, "workgroup", "local");
  __builtin_amdgcn_s_barrier();
  __builtin_amdgcn_fence(__ATOMIC_ACQUIRE, "workgroup", "local");
}
static __device__ __forceinline__ float fast_tanh(float x) {
  float xc = fminf(fmaxf(x, -15.f), 15.f);
  return 1.f - 2.f * __builtin_amdgcn_rcpf(__expf(2.f * xc) + 1.f);
}

// ---------------- dtype detection ----------------
__global__ void k_detect(const void* __restrict__ fact, int* __restrict__ mode) {
  int tid = threadIdx.x;  // 256
  const unsigned short* u = (const unsigned short*)fact;
  float v = fabsf(b2f(u[2 * tid]));
  if (!(v == v)) v = 1e30f;
  for (int o = 32; o > 0; o >>= 1) v = fmaxf(v, __shfl_xor(v, o));
  __shared__ float red[4];
  int wave = tid >> 6, lane = tid & 63;
  if (lane == 0) red[wave] = v;
  __syncthreads();
  if (tid == 0) {
    float m = fmaxf(fmaxf(red[0], red[1]), fmaxf(red[2], red[3]));
    mode[0] = (m > 1e4f) ? 1 : 0;
  }
}

// ---------------- prep: packed bf16 weights ----------------
__global__ void k_prep_w(const void* __restrict__ W1,
                         const void* __restrict__ Wr,
                         const void* __restrict__ Wh,
                         const void* __restrict__ Ur,
                         const void* __restrict__ Uh,
                         const int* __restrict__ mode,
                         unsigned* __restrict__ W5q,
                         unsigned* __restrict__ Urp,
                         unsigned* __restrict__ Uhp) {
  int md = *mode;
  int idx = blockIdx.x * 256 + threadIdx.x;  // 0..32767
  int i = idx >> 8, j = idx & 255;
  Urp[idx] = (unsigned)ldb(Ur, (size_t)(2 * i) * 256 + j, md) |
             ((unsigned)ldb(Ur, (size_t)(2 * i + 1) * 256 + j, md) << 16);
  Uhp[idx] = (unsigned)ldb(Uh, (size_t)(2 * i) * 256 + j, md) |
             ((unsigned)ldb(Uh, (size_t)(2 * i + 1) * 256 + j, md) << 16);
  float v0, v1;
  int p;
  p = i;
  v0 = ldf(W1, (size_t)(2 * i) * 256 + j, md);
  v1 = ldf(W1, (size_t)(2 * i + 1) * 256 + j, md);
  W5q[(((p >> 2) * 256 + j) << 2) + (p & 3)] = (unsigned)f2b(v0) | ((unsigned)f2b(v1) << 16);
  p = 128 + i;
  v0 = ldf(W1, (size_t)(768 + 2 * i) * 256 + j, md) + ldf(W1, (size_t)(1024 + 2 * i) * 256 + j, md);
  v1 = ldf(W1, (size_t)(769 + 2 * i) * 256 + j, md) + ldf(W1, (size_t)(1025 + 2 * i) * 256 + j, md);
  W5q[(((p >> 2) * 256 + j) << 2) + (p & 3)] = (unsigned)f2b(v0) | ((unsigned)f2b(v1) << 16);
  p = 256 + i;
  v0 = ldf(W1, (size_t)(1280 + 2 * i) * 256 + j, md) + ldf(W1, (size_t)(1536 + 2 * i) * 256 + j, md);
  v1 = ldf(W1, (size_t)(1281 + 2 * i) * 256 + j, md) + ldf(W1, (size_t)(1537 + 2 * i) * 256 + j, md);
  W5q[(((p >> 2) * 256 + j) << 2) + (p & 3)] = (unsigned)f2b(v0) | ((unsigned)f2b(v1) << 16);
  p = 384 + i;
  v0 = ldf(Wr, (size_t)(2 * i) * 256 + j, md);
  v1 = ldf(Wr, (size_t)(2 * i + 1) * 256 + j, md);
  W5q[(((p >> 2) * 256 + j) << 2) + (p & 3)] = (unsigned)f2b(v0) | ((unsigned)f2b(v1) << 16);
  p = 512 + i;
  v0 = ldf(Wh, (size_t)(2 * i) * 256 + j, md);
  v1 = ldf(Wh, (size_t)(2 * i + 1) * 256 + j, md);
  W5q[(((p >> 2) * 256 + j) << 2) + (p & 3)] = (unsigned)f2b(v0) | ((unsigned)f2b(v1) << 16);
}

// ---------------- prep: q-dependent vectors ----------------
__global__ void k_prep_q(const void* __restrict__ q,
                         const void* __restrict__ W1,
                         const void* __restrict__ b1,
                         const void* __restrict__ Ws,
                         const void* __restrict__ bs,
                         const void* __restrict__ We,
                         const void* __restrict__ be,
                         const int* __restrict__ mode,
                         float* __restrict__ qw1,
                         float* __restrict__ qs,
                         float* __restrict__ qe) {
  __shared__ float qsh[256];
  __shared__ float reds[4], rede[4];
  int md = *mode;
  int b = blockIdx.x, tid = threadIdx.x;
  float qv = ldf(q, (size_t)b * 256 + tid, md);
  qsh[tid] = qv;
  __syncthreads();
  float acc = ldf(b1, tid, md);
  for (int i = 0; i < 256; ++i) {
    float w = ldf(W1, (size_t)(256 + i) * 256 + tid, md) + ldf(W1, (size_t)(512 + i) * 256 + tid, md);
    acc = fmaf(qsh[i], w, acc);
  }
  qw1[b * 256 + tid] = acc;
  float ps = qv * ldf(Ws, tid, md);
  float pe = qv * ldf(We, tid, md);
  for (int o = 32; o > 0; o >>= 1) { ps += __shfl_down(ps, o); pe += __shfl_down(pe, o); }
  int wave = tid >> 6, lane = tid & 63;
  if (lane == 0) { reds[wave] = ps; rede[wave] = pe; }
  __syncthreads();
  if (tid == 0) {
    qs[b] = ldf(bs, 0, md) + reds[0] + reds[1] + reds[2] + reds[3];
    qe[b] = ldf(be, 0, md) + rede[0] + rede[1] + rede[2] + rede[3];
  }
}

// ---------------- main GEMM via MFMA: att pre-softmax + xr/xh ----------------
__launch_bounds__(256, 2)
__global__ void k_main(const void* __restrict__ fact,
                       const void* __restrict__ q,
                       const unsigned* __restrict__ W5q,
                       const float* __restrict__ qw1,
                       const void* __restrict__ W2,
                       const void* __restrict__ b2v,
                       const void* __restrict__ br,
                       const void* __restrict__ bh,
                       const int* __restrict__ mode,
                       float* __restrict__ att,
                       unsigned* __restrict__ xrh) {
  __shared__ __align__(16) unsigned short A[16 * 776];
  __shared__ float wsc[64];
  int md = *mode;
  int blk = blockIdx.x;
  int b = blk >> 5, t0 = (blk & 31) * 16;
  int tid = threadIdx.x;
  {
    float qv = ldf(q, (size_t)b * 256 + tid, md);
    for (int r = 0; r < 16; ++r) {
      float f = ldf(fact, ((size_t)(b * 512 + t0 + r)) * 256 + tid, md);
      A[r * 776 + tid] = f2b(f);
      A[r * 776 + 256 + tid] = f2b(f * qv);
      A[r * 776 + 512 + tid] = f2b(fabsf(f - qv));
    }
  }
  __syncthreads();
  int wv = tid >> 6, lane = tid & 63;
  int n16 = lane & 15, quad = lane >> 4;
  int colb = wv * 64 + n16;
  const uint4* W4 = (const uint4*)W5q;
  f32x4 z = {0.f, 0.f, 0.f, 0.f};
  f32x4 u[4] = {z, z, z, z}, ar[4] = {z, z, z, z}, ah[4] = {z, z, z, z};
#pragma unroll
  for (int kc = 0; kc < 8; ++kc) {
    uint4 av = *(const uint4*)((const char*)A + n16 * 1552 + kc * 64 + quad * 16);
    bfrag af = __builtin_bit_cast(bfrag, av);
    int pg = kc * 4 + quad;
#pragma unroll
    for (int tile = 0; tile < 4; ++tile) {
      int col = colb + tile * 16;
      uint4 bu = W4[(size_t)pg * 256 + col];
      uint4 bw = W4[(size_t)(96 + pg) * 256 + col];
      uint4 bv = W4[(size_t)(128 + pg) * 256 + col];
      u[tile] = __builtin_amdgcn_mfma_f32_16x16x32_bf16(af, __builtin_bit_cast(bfrag, bu), u[tile], 0, 0, 0);
      ar[tile] = __builtin_amdgcn_mfma_f32_16x16x32_bf16(af, __builtin_bit_cast(bfrag, bw), ar[tile], 0, 0, 0);
      ah[tile] = __builtin_amdgcn_mfma_f32_16x16x32_bf16(af, __builtin_bit_cast(bfrag, bv), ah[tile], 0, 0, 0);
    }
  }
#pragma unroll
  for (int kc = 8; kc < 24; ++kc) {
    uint4 av = *(const uint4*)((const char*)A + n16 * 1552 + kc * 64 + quad * 16);
    bfrag af = __builtin_bit_cast(bfrag, av);
    int pg = kc * 4 + quad;
#pragma unroll
    for (int tile = 0; tile < 4; ++tile) {
      int col = colb + tile * 16;
      uint4 bu = W4[(size_t)pg * 256 + col];
      u[tile] = __builtin_amdgcn_mfma_f32_16x16x32_bf16(af, __builtin_bit_cast(bfrag, bu), u[tile], 0, 0, 0);
    }
  }
  float qwv[4], w2v[4], brv[4], bhv[4];
#pragma unroll
  for (int tile = 0; tile < 4; ++tile) {
    int col = colb + tile * 16;
    qwv[tile] = qw1[b * 256 + col];
    w2v[tile] = ldf(W2, col, md);
    brv[tile] = ldf(br, col, md);
    bhv[tile] = ldf(bh, col, md);
  }
  float ps[4];
#pragma unroll
  for (int reg = 0; reg < 4; ++reg) {
    float p = 0.f;
#pragma unroll
    for (int tile = 0; tile < 4; ++tile) {
      float hid = fast_tanh(u[tile][reg] + qwv[tile]);
      p = fmaf(hid, w2v[tile], p);
    }
    ps[reg] = red16(p);
  }
  if (n16 == 0) {
#pragma unroll
    for (int reg = 0; reg < 4; ++reg) wsc[wv * 16 + quad * 4 + reg] = ps[reg];
  }
  __syncthreads();
  if (tid < 16) {
    att[b * 512 + t0 + tid] =
        wsc[tid] + wsc[16 + tid] + wsc[32 + tid] + wsc[48 + tid] + ldf(b2v, 0, md);
  }
#pragma unroll
  for (int tile = 0; tile < 4; ++tile) {
    int col = colb + tile * 16;
#pragma unroll
    for (int reg = 0; reg < 4; ++reg) {
      int t = t0 + quad * 4 + reg;
      unsigned v = (unsigned)f2b(ar[tile][reg] + brv[tile]) |
                   ((unsigned)f2b(ah[tile][reg] + bhv[tile]) << 16);
      xrh[((size_t)(b * 512 + t)) * 256 + col] = v;
    }
  }
}

// ---------------- softmax over T per batch ----------------
__global__ void k_softmax(const float* __restrict__ att, float* __restrict__ g) {
  __shared__ float red[8];
  int b = blockIdx.x, tid = threadIdx.x;  // 512 threads
  float v = att[b * 512 + tid];
  float m = v;
  for (int o = 32; o > 0; o >>= 1) m = fmaxf(m, __shfl_xor(m, o));
  int wave = tid >> 6, lane = tid & 63;
  if (lane == 0) red[wave] = m;
  __syncthreads();
  m = red[0];
#pragma unroll
  for (int w = 1; w < 8; ++w) m = fmaxf(m, red[w]);
  float e = __expf(v - m);
  float s = e;
  for (int o = 32; o > 0; o >>= 1) s += __shfl_xor(s, o);
  __syncthreads();
  if (lane == 0) red[wave] = s;
  __syncthreads();
  s = red[0] + red[1] + red[2] + red[3] + red[4] + red[5] + red[6] + red[7];
  g[b * 512 + tid] = e / s;
}

// ---------------- MFMA GRU scan: 4 batches/block, 16 blocks, 8 waves ----------------
// 512 threads = 8 waves. Wave wv owns cols [wv*32, wv*32+32); B-frags uint4 in
// regs. A rows: row m holds batch m>>2 -> lane (n16,quad) finalizes
// (batch=quad, col0/col1). LDS per step is ONLY the cross-wave h/rh exchange:
// 16 fragment b128 reads + 4 b16 writes per wave, 2 barriers. All lane-private
// data (xc gate inputs, g, e-outputs) bypasses LDS: xc/g are register-
// prefetched one 8-step block ahead (double-buffered), e-outputs go straight
// to global ep (2 u16 stores/step).
__launch_bounds__(512, 2)
__global__ void k_scan(const unsigned* __restrict__ Urp,
                       const unsigned* __restrict__ Uhp,
                       const unsigned* __restrict__ xrh,
                       const float* __restrict__ g,
                       const int* __restrict__ input_len,
                       unsigned short* __restrict__ ep) {
  __shared__ __align__(16) unsigned short hB[4 * 272];
  __shared__ __align__(16) unsigned short rhB[4 * 272];
  int b0 = blockIdx.x * 4;
  int tid = threadIdx.x;  // 0..511
  int wv = tid >> 6, lane = tid & 63;
  int n16 = lane & 15, quad = lane >> 4;
  int col0 = wv * 32 + n16;
  int col1 = col0 + 16;
  uint4 br4[2][8], bh4[2][8];
#pragma unroll
  for (int tile = 0; tile < 2; ++tile) {
    int col = wv * 32 + tile * 16 + n16;
#pragma unroll
    for (int kc = 0; kc < 8; ++kc) {
      int p = kc * 16 + quad * 4;
      uint4 rv = {Urp[(size_t)p * 256 + col], Urp[(size_t)(p + 1) * 256 + col],
                  Urp[(size_t)(p + 2) * 256 + col], Urp[(size_t)(p + 3) * 256 + col]};
      uint4 hv = {Uhp[(size_t)p * 256 + col], Uhp[(size_t)(p + 1) * 256 + col],
                  Uhp[(size_t)(p + 2) * 256 + col], Uhp[(size_t)(p + 3) * 256 + col]};
      br4[tile][kc] = rv;
      bh4[tile][kc] = hv;
    }
  }
  for (int i = tid; i < 4 * 272; i += 512) { hB[i] = 0; rhB[i] = 0; }
  int mylen = input_len[b0 + quad];
  float hm0 = 0.f, hm1 = 0.f;  // this lane's h for (batch=quad, col0/col1)
  const char* hbase = (const char*)hB + (n16 >> 2) * 544 + quad * 16;
  const char* rhbase = (const char*)rhB + (n16 >> 2) * 544 + quad * 16;
  const unsigned* xrow = xrh + (size_t)(b0 + quad) * 512 * 256;
  const float* grow = g + (size_t)(b0 + quad) * 512;
  unsigned short* eprow = ep + (size_t)(b0 + quad) * 512 * 256;

  unsigned xa[16], xbb[16];
  float4 ga0, ga1, gb0, gb1;
  auto prefetch = [&](int tb, unsigned (&xr)[16], float4& g0, float4& g1) {
    const unsigned* xp = xrow + (size_t)tb * 8 * 256;
#pragma unroll
    for (int s = 0; s < 8; ++s) {
      xr[2 * s] = xp[s * 256 + col0];
      xr[2 * s + 1] = xp[s * 256 + col1];
    }
    const float* gp = grow + tb * 8;
    g0 = *(const float4*)gp;
    g1 = *(const float4*)(gp + 4);
  };
  prefetch(0, xa, ga0, ga1);
  __syncthreads();
  const f32x4 z4 = {0.f, 0.f, 0.f, 0.f};

  auto step = [&](int T, unsigned XC0, unsigned XC1, float GT) {
    // ---- phase A: rpre = h @ Ur (2 tiles, depth-2 chains) ----
    f32x4 accA[2][4];
#pragma unroll
    for (int tl = 0; tl < 2; ++tl)
#pragma unroll
      for (int j = 0; j < 4; ++j) accA[tl][j] = z4;
#pragma unroll
    for (int kc = 0; kc < 8; ++kc) {
      uint4 av = *(const uint4*)(hbase + kc * 64);
      bfrag af = __builtin_bit_cast(bfrag, av);
      int j = kc & 3;
      accA[0][j] = __builtin_amdgcn_mfma_f32_16x16x32_bf16(af, __builtin_bit_cast(bfrag, br4[0][kc]), accA[0][j], 0, 0, 0);
      accA[1][j] = __builtin_amdgcn_mfma_f32_16x16x32_bf16(af, __builtin_bit_cast(bfrag, br4[1][kc]), accA[1][j], 0, 0, 0);
    }
    {
      float v0 = (accA[0][0][0] + accA[0][1][0]) + (accA[0][2][0] + accA[0][3][0]);
      float v1 = (accA[1][0][0] + accA[1][1][0]) + (accA[1][2][0] + accA[1][3][0]);
      float e0 = __expf(-(v0 + blo(XC0)));
      float e1 = __expf(-(v1 + blo(XC1)));
      float r0 = __builtin_amdgcn_rcpf(1.f + e0);
      float r1 = __builtin_amdgcn_rcpf(1.f + e1);
      rhB[quad * 272 + col0] = f2b(r0 * hm0);
      rhB[quad * 272 + col1] = f2b(r1 * hm1);
    }
    sync_lds();
    // ---- phase B: hpre = (r*h) @ Uh ----
    f32x4 accB[2][4];
#pragma unroll
    for (int tl = 0; tl < 2; ++tl)
#pragma unroll
      for (int j = 0; j < 4; ++j) accB[tl][j] = z4;
#pragma unroll
    for (int kc = 0; kc < 8; ++kc) {
      uint4 av = *(const uint4*)(rhbase + kc * 64);
      bfrag af = __builtin_bit_cast(bfrag, av);
      int j = kc & 3;
      accB[0][j] = __builtin_amdgcn_mfma_f32_16x16x32_bf16(af, __builtin_bit_cast(bfrag, bh4[0][kc]), accB[0][j], 0, 0, 0);
      accB[1][j] = __builtin_amdgcn_mfma_f32_16x16x32_bf16(af, __builtin_bit_cast(bfrag, bh4[1][kc]), accB[1][j], 0, 0, 0);
    }
    {
      float w0 = (accB[0][0][0] + accB[0][1][0]) + (accB[0][2][0] + accB[0][3][0]);
      float w1 = (accB[1][0][0] + accB[1][1][0]) + (accB[1][2][0] + accB[1][3][0]);
      float c0 = fminf(fmaxf(w0 + bhi(XC0), -15.f), 15.f);
      float c1 = fminf(fmaxf(w1 + bhi(XC1), -15.f), 15.f);
      float hc0 = 1.f - 2.f * __builtin_amdgcn_rcpf(__expf(2.f * c0) + 1.f);
      float hc1 = 1.f - 2.f * __builtin_amdgcn_rcpf(__expf(2.f * c1) + 1.f);
      bool valid = T < mylen;
      float hn0 = hm0 + GT * (hc0 - hm0);
      float hn1 = hm1 + GT * (hc1 - hm1);
      hm0 = valid ? hn0 : hm0;
      hm1 = valid ? hn1 : hm1;
      unsigned short hb0 = f2b(hm0), hb1 = f2b(hm1);
      hB[quad * 272 + col0] = hb0;
      hB[quad * 272 + col1] = hb1;
      eprow[(size_t)T * 256 + col0] = valid ? hb0 : (unsigned short)0;
      eprow[(size_t)T * 256 + col1] = valid ? hb1 : (unsigned short)0;
    }
    sync_lds();
  };

  for (int tb2 = 0; tb2 < 32; ++tb2) {
    prefetch(2 * tb2 + 1, xbb, gb0, gb1);
#pragma unroll
    for (int tt = 0; tt < 8; ++tt)
      step(tb2 * 16 + tt, xa[2 * tt], xa[2 * tt + 1], tt < 4 ? ga0[tt] : ga1[tt - 4]);
    prefetch(tb2 < 31 ? 2 * tb2 + 2 : 63, xa, ga0, ga1);
#pragma unroll
    for (int tt = 0; tt < 8; ++tt)
      step(tb2 * 16 + 8 + tt, xbb[2 * tt], xbb[2 * tt + 1], tt < 4 ? gb0[tt] : gb1[tt - 4]);
  }
}

// ---------------- final dense: out_s/out_e (fp32 output) ----------------
__global__ void k_out(const unsigned short* __restrict__ ep,
                      const void* __restrict__ Ws,
                      const void* __restrict__ We,
                      const float* __restrict__ qs,
                      const float* __restrict__ qe,
                      const int* __restrict__ mode,
                      float* __restrict__ out) {
  int md = *mode;
  int tid = threadIdx.x;
  int wave = tid >> 6, lane = tid & 63;
  int row = blockIdx.x * 4 + wave;  // (b,t) flat, 0..32767
  const unsigned short* er = ep + (size_t)row * 256 + lane * 4;
  float f0 = b2f(er[0]), f1 = b2f(er[1]), f2 = b2f(er[2]), f3 = b2f(er[3]);
  int n = 256 + lane * 4;
  float s = f0 * ldf(Ws, n, md) + f1 * ldf(Ws, n + 1, md) + f2 * ldf(Ws, n + 2, md) + f3 * ldf(Ws, n + 3, md);
  float e = f0 * ldf(We, n, md) + f1 * ldf(We, n + 1, md) + f2 * ldf(We, n + 2, md) + f3 * ldf(We, n + 3, md);
  for (int o = 32; o > 0; o >>= 1) { s += __shfl_down(s, o); e += __shfl_down(e, o); }
  if (lane == 0) {
    int b = row >> 9;
    out[row] = tanhf(qs[b] + s);
    out[32768 + row] = tanhf(qe[b] + e);
  }
}

extern "C" void kernel_launch(void* const* d_in, const int* in_sizes, int n_in,
                              void* d_out, int out_size, void* d_ws, size_t ws_size,
                              hipStream_t stream) {
  const void* q    = d_in[0];
  const void* fact = d_in[1];
  const int* ilen  = (const int*)d_in[2];
  const void* W1   = d_in[3];
  const void* b1   = d_in[4];
  const void* W2   = d_in[5];
  const void* b2v  = d_in[6];
  const void* Wr   = d_in[7];
  const void* Ur   = d_in[8];
  const void* br   = d_in[9];
  const void* Wh   = d_in[10];
  const void* Uh   = d_in[11];
  const void* bh   = d_in[12];
  const void* Ws   = d_in[13];
  const void* bs   = d_in[14];
  const void* We   = d_in[15];
  const void* be   = d_in[16];

  char* w = (char*)d_ws;
  unsigned* W5q = (unsigned*)(w);
  unsigned* Urp = (unsigned*)(w + 1310720);
  unsigned* Uhp = (unsigned*)(w + 1441792);
  float*    qw1 = (float*)(w + 1572864);
  float*    qs  = (float*)(w + 1638400);
  float*    qe  = (float*)(w + 1638656);
  float*    att = (float*)(w + 1638912);
  float*    g   = (float*)(w + 1769984);
  unsigned* xrh = (unsigned*)(w + 1901056);
  unsigned short* ep = (unsigned short*)(w + 35455488);
  int*      mode = (int*)(w + 52232704);
  float* out = (float*)d_out;

  k_detect<<<dim3(1), dim3(256), 0, stream>>>(fact, mode);
  k_prep_w<<<dim3(128), dim3(256), 0, stream>>>(W1, Wr, Wh, Ur, Uh, mode, W5q, Urp, Uhp);
  k_prep_q<<<dim3(64), dim3(256), 0, stream>>>(q, W1, b1, Ws, bs, We, be, mode, qw1, qs, qe);
  k_main<<<dim3(2048), dim3(256), 0, stream>>>(fact, q, W5q, qw1, W2, b2v, br, bh, mode, att, xrh);
  k_softmax<<<dim3(64), dim3(512), 0, stream>>>(att, g);
  k_scan<<<dim3(16), dim3(512), 0, stream>>>(Urp, Uhp, xrh, g, ilen, ep);
  k_out<<<dim3(8192), dim3(256), 0, stream>>>(ep, Ws, We, qs, qe, mode, out);
}